// Round 14
// baseline (145.987 us; speedup 1.0000x reference)
//
#include <hip/hip_runtime.h>

#define N_NODES  50000
#define N_EDGES  600000
#define CHANNELS 128
#define HEADS    8
#define HEAD_DIM 16     // CHANNELS / HEADS
#define CAP      64     // per-node capacity; degrees ~ Poisson(12), max ~28

#define NBINS    256    // dst bins; bin = dst*NBINS/N_NODES (~196 nodes/bin)
#define CHUNK_E  1024   // edges per chunk
#define NCHUNK   ((N_EDGES + CHUNK_E - 1) / CHUNK_E)     // 586
#define SEGCAP   2816   // per-bin edge segment capacity (mean 2344, +~10 sigma)

#define SUBB     8      // sub-blocks per bin in the fused kernel
#define NPB      25     // max nodes per sub-block (196/8 rounded up)

#define LOGIT_VB ((N_NODES * (CHANNELS / 4)) / 256)      // 6250
#define WPB      4      // waves per block in the fused kernel

// ---------------------------------------------------------------------------
// A: per-chunk LDS histogram over dst bins (bin-major store so the scan reads
//    coalesced), plus the per-node logit halves + bf16(x) sweep as extra blocks.
// ---------------------------------------------------------------------------
__global__ void hist_logit_kernel(const float* __restrict__ x,
                                  const float* __restrict__ att,
                                  const int*   __restrict__ dst,
                                  int*            __restrict__ hist,   // [bin][chunk]
                                  float*          __restrict__ ls8,
                                  float*          __restrict__ ld8,
                                  unsigned short* __restrict__ xb) {
    int b = blockIdx.x;
    int t = threadIdx.x;
    if (b < NCHUNK) {
        __shared__ int lh[NBINS];
        lh[t] = 0;
        __syncthreads();
        int base = b * CHUNK_E;
#pragma unroll
        for (int k = 0; k < 4; ++k) {
            int e = base + t + k * 256;
            if (e < N_EDGES) {
                unsigned bin = (unsigned)(dst[e] * NBINS) / N_NODES;
                atomicAdd(&lh[bin], 1);          // LDS atomic
            }
        }
        __syncthreads();
        hist[t * NCHUNK + b] = lh[t];            // bin-major (scattered, tiny)
    } else {
        int gid = (b - NCHUNK) * 256 + t;        // (node, float4-slot)
        int n  = gid >> 5;                       // 32 float4s per node
        int c4 = gid & 31;
        int h  = c4 >> 2;
        int j4 = c4 & 3;

        float4 v = ((const float4*)x)[gid];

        // bf16 round-to-nearest-even, packed 8B store
        unsigned int ux = __float_as_uint(v.x), uy = __float_as_uint(v.y);
        unsigned int uz = __float_as_uint(v.z), uw = __float_as_uint(v.w);
        ushort4 pk;
        pk.x = (unsigned short)((ux + 0x7FFFu + ((ux >> 16) & 1u)) >> 16);
        pk.y = (unsigned short)((uy + 0x7FFFu + ((uy >> 16) & 1u)) >> 16);
        pk.z = (unsigned short)((uz + 0x7FFFu + ((uz >> 16) & 1u)) >> 16);
        pk.w = (unsigned short)((uw + 0x7FFFu + ((uw >> 16) & 1u)) >> 16);
        ((ushort4*)xb)[gid] = pk;

        float4 as4 = ((const float4*)att)[h * 8 + j4];
        float4 ad4 = ((const float4*)att)[h * 8 + 4 + j4];
        float ts = v.x * as4.x + v.y * as4.y + v.z * as4.z + v.w * as4.w;
        float td = v.x * ad4.x + v.y * ad4.y + v.z * ad4.z + v.w * ad4.w;
        ts += __shfl_xor(ts, 1, 4); ts += __shfl_xor(ts, 2, 4);
        td += __shfl_xor(td, 1, 4); td += __shfl_xor(td, 2, 4);
        if (j4 == 0) {
            ls8[n * HEADS + h] = ts;
            ld8[n * HEADS + h] = td;
        }
    }
}

// ---------------------------------------------------------------------------
// B: per-bin exclusive allocation over chunks.  One 256-thread block per bin;
// thread t owns chunks {t, t+256, t+512}.  Coalesced bin-major reads,
// 8-round LDS scan of the 256 per-thread sums.
// ---------------------------------------------------------------------------
__global__ void scan_kernel(const int* __restrict__ hist,   // [bin][chunk]
                            int* __restrict__ offm,         // [chunk][bin]
                            int* __restrict__ bincnt) {
    __shared__ int lds[256];
    int bin = blockIdx.x;
    int t = threadIdx.x;
    int c0 = t, c1 = t + 256, c2 = t + 512;
    int v0 = hist[bin * NCHUNK + c0];                        // c0 < 586 always
    int v1 = (c1 < NCHUNK) ? hist[bin * NCHUNK + c1] : 0;
    int v2 = (c2 < NCHUNK) ? hist[bin * NCHUNK + c2] : 0;
    int s = v0 + v1 + v2;
    lds[t] = s;
    __syncthreads();
    for (int off = 1; off < 256; off <<= 1) {
        int u = (t >= off) ? lds[t - off] : 0;
        __syncthreads();
        lds[t] += u;
        __syncthreads();
    }
    int base = lds[t] - s;                                   // exclusive
    offm[c0 * NBINS + bin] = base;
    if (c1 < NCHUNK) offm[c1 * NBINS + bin] = base + v0;
    if (c2 < NCHUNK) offm[c2 * NBINS + bin] = base + v0 + v1;
    if (t == 255) bincnt[bin] = lds[255];
}

// ---------------------------------------------------------------------------
// C: deterministic scatter of packed (src,dst) into per-bin segments.
// Rank within (chunk,bin) via LDS atomic; global slot = offm + rank.
// ---------------------------------------------------------------------------
__global__ void binscatter_kernel(const int* __restrict__ src,
                                  const int* __restrict__ dst,
                                  const int* __restrict__ offm,   // [chunk][bin]
                                  unsigned*  __restrict__ ebuf) {
    __shared__ int loff[NBINS];
    __shared__ int lcnt[NBINS];
    int b = blockIdx.x;
    int t = threadIdx.x;
    loff[t] = offm[b * NBINS + t];
    lcnt[t] = 0;
    __syncthreads();
    int base = b * CHUNK_E;
#pragma unroll
    for (int k = 0; k < 4; ++k) {
        int e = base + t + k * 256;
        if (e < N_EDGES) {
            int d = dst[e];
            int s = src[e];
            unsigned bin = (unsigned)(d * NBINS) / N_NODES;
            int r = atomicAdd(&lcnt[bin], 1) + loff[bin];   // LDS atomic
            if (r < SEGCAP)
                ebuf[(size_t)bin * SEGCAP + r] = (unsigned)s | ((unsigned)d << 16);
        }
    }
}

// ---------------------------------------------------------------------------
// D (merged bucket+fused): one block per (bin, 1/8 node sub-range).
// Build: stream the bin's ebuf segment (L2-resident after first of 8 reads),
//   range-filter for this block's ~25 nodes, LDS-atomic rank into LDS rows.
// Process (R11-proven body, all window indices STATIC): per node,
//   pass 1 (h=lane>>3, j=lane&7): logits in registers, 8-lane shuffle max
//     (clamped at 0 == reference's max(seg_max,0)), one exp per (edge,head)
//     -> LDS, denominator reduced in-register.
//   pass 2 (r=lane>>5, l32=lane&31): two edges per wave-load (uint2/lane,
//     half-wave = one 256B bf16 row), 8-slot statically-indexed shift window.
//   NOTE: q[]/av[] must only be indexed by compile-time constants — dynamic
//   indexing spills the window (R12: 72KB LDS/block, 3.6x regression).
// ---------------------------------------------------------------------------
__global__ void binfused_kernel(const unsigned* __restrict__ ebuf,
                                const int*      __restrict__ bincnt,
                                const unsigned short* __restrict__ xb,
                                const float* __restrict__ ls8,
                                const float* __restrict__ ld8,
                                float*       __restrict__ out) {
    __shared__ unsigned short rows[NPB * CAP];   // 3.2 KB
    __shared__ int   lcnt[NPB];
    __shared__ float s_p[WPB * CAP * HEADS];     // 8 KB staged softmax numerators

    int bin = blockIdx.x >> 3;
    int sub = blockIdx.x & (SUBB - 1);
    int t   = threadIdx.x;

    int b0 = (bin * N_NODES + NBINS - 1) / NBINS;
    int b1 = ((bin + 1) * N_NODES + NBINS - 1) / NBINS;
    int bn = b1 - b0;                            // ~196
    int n0 = b0 + (sub * bn) / SUBB;
    int n1 = b0 + ((sub + 1) * bn) / SUBB;
    int nn = n1 - n0;                            // <= 25

    if (t < NPB) lcnt[t] = 0;
    __syncthreads();

    int scnt = min(bincnt[bin], SEGCAP);
    for (int i = t; i < scnt; i += 256) {
        unsigned rec = ebuf[(size_t)bin * SEGCAP + i];
        int d = (int)(rec >> 16);
        if (d >= n0 && d < n1) {
            int pos = atomicAdd(&lcnt[d - n0], 1);          // LDS atomic
            if (pos < CAP) rows[(d - n0) * CAP + pos] = (unsigned short)(rec & 0xFFFFu);
        }
    }
    __syncthreads();

    int wave = t >> 6;
    int lane = t & 63;
    int h = lane >> 3;                           // pass-1 head
    int j = lane & 7;
    int r   = lane >> 5;                         // pass-2: which edge of pair
    int l32 = lane & 31;                         // pass-2: channel quad
    int h2  = l32 >> 2;                          // pass-2 head
    float* sp = s_p + wave * (CAP * HEADS);

    for (int nl = wave; nl < nn; nl += WPB) {
        int n = n0 + nl;
        int cnt = lcnt[nl];
        cnt = (cnt > CAP) ? CAP : cnt;
        int   myidx = (int)rows[nl * CAP + lane];
        float ldst  = ld8[n * HEADS + h];

        // ---- pass 1: logits in registers, per-head max, one exp per value ----
        float av[8];
        float mymax = -1e30f;
#pragma unroll
        for (int k = 0; k < 8; ++k) {
            int i = j + 8 * k;
            av[k] = -1e30f;
            if (i < cnt) {
                int   s  = __shfl(myidx, i);
                float lg = ls8[s * HEADS + h] + ldst;
                float a  = (lg >= 0.0f) ? lg : 0.2f * lg;   // LeakyReLU(0.2)
                av[k] = a;
                mymax = fmaxf(mymax, a);
            }
        }
#pragma unroll
        for (int o = 4; o >= 1; o >>= 1) mymax = fmaxf(mymax, __shfl_xor(mymax, o, 8));
        float m = fmaxf(mymax, 0.0f);            // reference clamps seg_max at 0

        float myl = 0.0f;
#pragma unroll
        for (int k = 0; k < 8; ++k) {
            int i = j + 8 * k;
            if (i < cnt) {
                float p = __expf(av[k] - m);
                sp[i * HEADS + h] = p;           // 2-way bank aliasing only
                myl += p;
            }
        }
#pragma unroll
        for (int o = 4; o >= 1; o >>= 1) myl += __shfl_xor(myl, o, 8);

        // ---- pass 2: weighted accumulate, 2 edges/load, window 8 slots ----
#define LP(k) ( ((const uint2*)(xb + (size_t)__shfl(myidx, ((2*(k)+r) < cnt) ? (2*(k)+r) : 0) * CHANNELS))[l32] )
        uint2 q[8];
#pragma unroll
        for (int k = 0; k < 8; ++k) q[k] = LP(k);

        float a0 = 0.f, a1 = 0.f, a2 = 0.f, a3 = 0.f;
        int npair = (cnt + 1) >> 1;
        int k = 0;
        for (; k + 4 <= npair; k += 4) {
#pragma unroll
            for (int u = 0; u < 4; ++u) {
                int e2 = 2 * (k + u) + r;
                float p = (e2 < cnt) ? sp[e2 * HEADS + h2] : 0.0f;
                uint2 qq = q[u];
                a0 += p * __uint_as_float(qq.x << 16);
                a1 += p * __uint_as_float(qq.x & 0xFFFF0000u);
                a2 += p * __uint_as_float(qq.y << 16);
                a3 += p * __uint_as_float(qq.y & 0xFFFF0000u);
            }
#pragma unroll
            for (int u = 0; u < 4; ++u) q[u] = q[u + 4];
#pragma unroll
            for (int u = 0; u < 4; ++u) q[u + 4] = LP(k + 8 + u);
        }
        for (; k < npair; ++k) {                 // tail 0..3 pairs
            int e2 = 2 * k + r;
            float p = (e2 < cnt) ? sp[e2 * HEADS + h2] : 0.0f;
            uint2 qq = q[0];
            a0 += p * __uint_as_float(qq.x << 16);
            a1 += p * __uint_as_float(qq.x & 0xFFFF0000u);
            a2 += p * __uint_as_float(qq.y << 16);
            a3 += p * __uint_as_float(qq.y & 0xFFFF0000u);
#pragma unroll
            for (int u = 0; u < 7; ++u) q[u] = q[u + 1];
        }
#undef LP

        a0 += __shfl_xor(a0, 32);
        a1 += __shfl_xor(a1, 32);
        a2 += __shfl_xor(a2, 32);
        a3 += __shfl_xor(a3, 32);

        float denom = __shfl(myl, h2 * 8);
        float inv = 1.0f / fmaxf(denom, 1e-10f);

        if (lane < 32) {
            float4 o4 = make_float4(a0 * inv, a1 * inv, a2 * inv, a3 * inv);
            ((float4*)(out + (size_t)n * CHANNELS))[l32] = o4;
        }
    }
}

// ---------------------------------------------------------------------------
extern "C" void kernel_launch(void* const* d_in, const int* in_sizes, int n_in,
                              void* d_out, int out_size, void* d_ws, size_t ws_size,
                              hipStream_t stream) {
    const float* x   = (const float*)d_in[0];
    const int*   ei  = (const int*)  d_in[1];   // (2, N_EDGES) row-major
    const float* att = (const float*)d_in[2];
    const int* src = ei;
    const int* dst = ei + N_EDGES;
    float* out = (float*)d_out;

    // Workspace layout (no memsets needed — every read location written first):
    int*            hist   = (int*)d_ws;                       // NBINS*NCHUNK
    int*            offm   = hist + (size_t)NBINS * NCHUNK;    // NCHUNK*NBINS
    int*            bincnt = offm + (size_t)NCHUNK * NBINS;    // NBINS
    unsigned*       ebuf   = (unsigned*)(bincnt + NBINS);      // NBINS*SEGCAP
    float*          ls8    = (float*)(ebuf + (size_t)NBINS * SEGCAP);
    float*          ld8    = ls8 + (size_t)N_NODES * HEADS;
    unsigned short* xb     = (unsigned short*)(ld8 + (size_t)N_NODES * HEADS);

    hist_logit_kernel<<<NCHUNK + LOGIT_VB, 256, 0, stream>>>(
        x, att, dst, hist, ls8, ld8, xb);
    scan_kernel<<<NBINS, 256, 0, stream>>>(hist, offm, bincnt);
    binscatter_kernel<<<NCHUNK, 256, 0, stream>>>(src, dst, offm, ebuf);
    binfused_kernel<<<NBINS * SUBB, 64 * WPB, 0, stream>>>(
        ebuf, bincnt, xb, ls8, ld8, out);
}

// Round 15
// 136.514 us; speedup vs baseline: 1.0694x; 1.0694x over previous
//
#include <hip/hip_runtime.h>

#define N_NODES  50000
#define N_EDGES  600000
#define CHANNELS 128
#define HEADS    8
#define HEAD_DIM 16     // CHANNELS / HEADS
#define CAP      64     // per-node capacity; degrees ~ Poisson(12), max ~28

#define NBINS    256    // dst bins; bin = dst*NBINS/N_NODES (~196 nodes/bin)
#define CHUNK_E  1024   // edges per chunk
#define NCHUNK   ((N_EDGES + CHUNK_E - 1) / CHUNK_E)     // 586
#define SEGCAP   2816   // per-bin edge segment capacity (mean 2344, +~10 sigma)
#define NPB      200    // max nodes per bin (196) rounded up

#define LOGIT_VB ((N_NODES * (CHANNELS / 8)) / 256)      // 3125 (8 channels/thread)
#define WPB      4      // waves (nodes) per block in the fused kernel

// bf16 round-to-nearest-even of an fp32 bit pattern
__device__ __forceinline__ unsigned bf16rne(float f) {
    unsigned u = __float_as_uint(f);
    return (u + 0x7FFFu + ((u >> 16) & 1u)) >> 16;
}

// ---------------------------------------------------------------------------
// A: per-chunk LDS histogram over dst bins (bin-major store so the scan reads
//    coalesced), plus the per-node logit halves + bf16(x) sweep as extra
//    blocks (8 channels per thread: 32B in, 16B packed-bf16 out).
// ---------------------------------------------------------------------------
__global__ void hist_logit_kernel(const float* __restrict__ x,
                                  const float* __restrict__ att,
                                  const int*   __restrict__ dst,
                                  int*            __restrict__ hist,   // [bin][chunk]
                                  float*          __restrict__ ls8,
                                  float*          __restrict__ ld8,
                                  unsigned short* __restrict__ xb) {
    int b = blockIdx.x;
    int t = threadIdx.x;
    if (b < NCHUNK) {
        __shared__ int lh[NBINS];
        lh[t] = 0;
        __syncthreads();
        int base = b * CHUNK_E;
#pragma unroll
        for (int k = 0; k < 4; ++k) {
            int e = base + t + k * 256;
            if (e < N_EDGES) {
                unsigned bin = (unsigned)(dst[e] * NBINS) / N_NODES;
                atomicAdd(&lh[bin], 1);          // LDS atomic
            }
        }
        __syncthreads();
        hist[t * NCHUNK + b] = lh[t];            // bin-major (scattered, tiny)
    } else {
        int gid = (b - NCHUNK) * 256 + t;        // (node, 8-channel slot)
        int n  = gid >> 4;                       // 16 slots per node
        int c8 = gid & 15;
        int h  = c8 >> 1;                        // 2 slots per head
        int j8 = c8 & 1;

        const float4* xp = (const float4*)x + (size_t)gid * 2;
        float4 v0 = xp[0], v1 = xp[1];

        // packed bf16 store: 8 channels -> uint4 (16B)
        uint4 pk;
        pk.x = bf16rne(v0.x) | (bf16rne(v0.y) << 16);
        pk.y = bf16rne(v0.z) | (bf16rne(v0.w) << 16);
        pk.z = bf16rne(v1.x) | (bf16rne(v1.y) << 16);
        pk.w = bf16rne(v1.z) | (bf16rne(v1.w) << 16);
        ((uint4*)xb)[gid] = pk;

        // att row = 32 floats = 8 float4s: [a_src(4), a_dst(4)]
        const float4* att4 = (const float4*)att;
        float4 as0 = att4[h * 8 + j8 * 2],     as1 = att4[h * 8 + j8 * 2 + 1];
        float4 ad0 = att4[h * 8 + 4 + j8 * 2], ad1 = att4[h * 8 + 5 + j8 * 2];
        float ts = v0.x*as0.x + v0.y*as0.y + v0.z*as0.z + v0.w*as0.w
                 + v1.x*as1.x + v1.y*as1.y + v1.z*as1.z + v1.w*as1.w;
        float td = v0.x*ad0.x + v0.y*ad0.y + v0.z*ad0.z + v0.w*ad0.w
                 + v1.x*ad1.x + v1.y*ad1.y + v1.z*ad1.z + v1.w*ad1.w;
        ts += __shfl_xor(ts, 1, 2);
        td += __shfl_xor(td, 1, 2);
        if (j8 == 0) {
            ls8[n * HEADS + h] = ts;
            ld8[n * HEADS + h] = td;
        }
    }
}

// ---------------------------------------------------------------------------
// B: per-bin exclusive allocation over chunks.  One 256-thread block per bin;
// thread t owns chunks {t, t+256, t+512}.  Coalesced bin-major reads,
// 8-round LDS scan of the 256 per-thread sums.
// ---------------------------------------------------------------------------
__global__ void scan_kernel(const int* __restrict__ hist,   // [bin][chunk]
                            int* __restrict__ offm,         // [chunk][bin]
                            int* __restrict__ bincnt) {
    __shared__ int lds[256];
    int bin = blockIdx.x;
    int t = threadIdx.x;
    int c0 = t, c1 = t + 256, c2 = t + 512;
    int v0 = hist[bin * NCHUNK + c0];                        // c0 < 586 always
    int v1 = (c1 < NCHUNK) ? hist[bin * NCHUNK + c1] : 0;
    int v2 = (c2 < NCHUNK) ? hist[bin * NCHUNK + c2] : 0;
    int s = v0 + v1 + v2;
    lds[t] = s;
    __syncthreads();
    for (int off = 1; off < 256; off <<= 1) {
        int u = (t >= off) ? lds[t - off] : 0;
        __syncthreads();
        lds[t] += u;
        __syncthreads();
    }
    int base = lds[t] - s;                                   // exclusive
    offm[c0 * NBINS + bin] = base;
    if (c1 < NCHUNK) offm[c1 * NBINS + bin] = base + v0;
    if (c2 < NCHUNK) offm[c2 * NBINS + bin] = base + v0 + v1;
    if (t == 255) bincnt[bin] = lds[255];
}

// ---------------------------------------------------------------------------
// C: deterministic scatter of packed (src,dst) into per-bin segments.
// Rank within (chunk,bin) via LDS atomic; global slot = offm + rank.
// ---------------------------------------------------------------------------
__global__ void binscatter_kernel(const int* __restrict__ src,
                                  const int* __restrict__ dst,
                                  const int* __restrict__ offm,   // [chunk][bin]
                                  unsigned*  __restrict__ ebuf) {
    __shared__ int loff[NBINS];
    __shared__ int lcnt[NBINS];
    int b = blockIdx.x;
    int t = threadIdx.x;
    loff[t] = offm[b * NBINS + t];
    lcnt[t] = 0;
    __syncthreads();
    int base = b * CHUNK_E;
#pragma unroll
    for (int k = 0; k < 4; ++k) {
        int e = base + t + k * 256;
        if (e < N_EDGES) {
            int d = dst[e];
            int s = src[e];
            unsigned bin = (unsigned)(d * NBINS) / N_NODES;
            int r = atomicAdd(&lcnt[bin], 1) + loff[bin];   // LDS atomic
            if (r < SEGCAP)
                ebuf[(size_t)bin * SEGCAP + r] = (unsigned)s | ((unsigned)d << 16);
        }
    }
}

// ---------------------------------------------------------------------------
// D: one block per bin — coalesced read of the bin's edge segment, LDS-atomic
// rank into per-node LDS rows, then one coalesced uint4 copy to the global
// bucket (replaces 600k scattered 2B stores).
// ---------------------------------------------------------------------------
__global__ void bucket_kernel(const unsigned* __restrict__ ebuf,
                              const int*      __restrict__ bincnt,
                              int*            __restrict__ cursor,
                              unsigned short* __restrict__ bucket) {
    __shared__ unsigned short rows[NPB * CAP];   // 25.6 KB
    __shared__ int lcnt[NPB];
    int b = blockIdx.x;
    int t = threadIdx.x;
    int n0 = (b * N_NODES + NBINS - 1) / NBINS;
    int n1 = ((b + 1) * N_NODES + NBINS - 1) / NBINS;
    int nn = n1 - n0;
    if (t < NPB) lcnt[t] = 0;
    __syncthreads();
    int cnt = min(bincnt[b], SEGCAP);
    for (int i = t; i < cnt; i += 256) {
        unsigned rec = ebuf[(size_t)b * SEGCAP + i];
        int s = (int)(rec & 0xFFFFu);
        int d = (int)(rec >> 16);
        int pos = atomicAdd(&lcnt[d - n0], 1);              // LDS atomic
        if (pos < CAP) rows[(d - n0) * CAP + pos] = (unsigned short)s;
    }
    __syncthreads();
    // coalesced LDS -> global copy (slots >= count are garbage, never
    // dereferenced past cnt by the fused kernel)
    int nq = nn * (CAP * 2 / 16);                // nn * 8 uint4s
    uint4* gdst = (uint4*)(bucket + (size_t)n0 * CAP);
    const uint4* lsrc = (const uint4*)rows;
    for (int i = t; i < nq; i += 256) gdst[i] = lsrc[i];
    if (t < nn) cursor[n0 + t] = lcnt[t];
}

// ---------------------------------------------------------------------------
// Fused GAT aggregation (R11-proven body — all window indices STATIC).
// One wave per node.
// Pass 1 (h=lane>>3, j=lane&7): logits in registers, 8-lane shuffle max
//   (clamped at 0 == reference's max(seg_max,0)), one exp per (edge,head)
//   -> LDS, denominator reduced in-register.
// Pass 2 (r=lane>>5, l32=lane&31): two edges per wave-load (uint2/lane,
//   half-wave = one 256B bf16 row), 8-slot statically-indexed shift window
//   = 16 edges in flight.  NOTE: q[] must only ever be indexed by
//   compile-time constants — dynamic indexing spills the window (R12: 72KB
//   LDS/block, 3.6x regression).
// ---------------------------------------------------------------------------
__global__ void fused_gat_kernel(const unsigned short* __restrict__ xb,
                                 const float* __restrict__ ls8,
                                 const float* __restrict__ ld8,
                                 const int*   __restrict__ cursor,
                                 const unsigned short* __restrict__ bucket,
                                 float*       __restrict__ out) {
    __shared__ float s_p[WPB * CAP * HEADS];     // 8 KB: staged softmax numerators

    int wave = threadIdx.x >> 6;
    int lane = threadIdx.x & 63;
    int n = blockIdx.x * WPB + wave;
    if (n >= N_NODES) return;
    int h = lane >> 3;                           // pass-1 head
    int j = lane & 7;
    int r   = lane >> 5;                         // pass-2: which edge of pair
    int l32 = lane & 31;                         // pass-2: channel quad
    int h2  = l32 >> 2;                          // pass-2 head

    int   cnt_raw = cursor[n];
    int   myidx   = (int)bucket[(size_t)n * CAP + lane];
    float ldst    = ld8[n * HEADS + h];
    int cnt = (cnt_raw > CAP) ? CAP : cnt_raw;

    float* sp = s_p + wave * (CAP * HEADS);

    // ---- pass 1: logits in registers, per-head max, single exp per value ----
    float av[8];
    float mymax = -1e30f;
#pragma unroll
    for (int k = 0; k < 8; ++k) {
        int i = j + 8 * k;
        av[k] = -1e30f;
        if (i < cnt) {
            int   s  = __shfl(myidx, i);
            float lg = ls8[s * HEADS + h] + ldst;
            float a  = (lg >= 0.0f) ? lg : 0.2f * lg;   // LeakyReLU(0.2)
            av[k] = a;
            mymax = fmaxf(mymax, a);
        }
    }
#pragma unroll
    for (int o = 4; o >= 1; o >>= 1) mymax = fmaxf(mymax, __shfl_xor(mymax, o, 8));
    float m = fmaxf(mymax, 0.0f);                // reference clamps seg_max at 0

    float myl = 0.0f;
#pragma unroll
    for (int k = 0; k < 8; ++k) {
        int i = j + 8 * k;
        if (i < cnt) {
            float p = __expf(av[k] - m);
            sp[i * HEADS + h] = p;               // 2-way bank aliasing only
            myl += p;
        }
    }
#pragma unroll
    for (int o = 4; o >= 1; o >>= 1) myl += __shfl_xor(myl, o, 8);

    // ---- pass 2: weighted accumulate, 2 edges/load, window 8 slots ----
#define LP(k) ( ((const uint2*)(xb + (size_t)__shfl(myidx, ((2*(k)+r) < cnt) ? (2*(k)+r) : 0) * CHANNELS))[l32] )
    uint2 q[8];
#pragma unroll
    for (int k = 0; k < 8; ++k) q[k] = LP(k);

    float a0 = 0.f, a1 = 0.f, a2 = 0.f, a3 = 0.f;
    int npair = (cnt + 1) >> 1;
    int k = 0;
    for (; k + 4 <= npair; k += 4) {
#pragma unroll
        for (int u = 0; u < 4; ++u) {
            int e2 = 2 * (k + u) + r;
            float p = (e2 < cnt) ? sp[e2 * HEADS + h2] : 0.0f;
            uint2 qq = q[u];
            a0 += p * __uint_as_float(qq.x << 16);
            a1 += p * __uint_as_float(qq.x & 0xFFFF0000u);
            a2 += p * __uint_as_float(qq.y << 16);
            a3 += p * __uint_as_float(qq.y & 0xFFFF0000u);
        }
#pragma unroll
        for (int u = 0; u < 4; ++u) q[u] = q[u + 4];
#pragma unroll
        for (int u = 0; u < 4; ++u) q[u + 4] = LP(k + 8 + u);
    }
    for (; k < npair; ++k) {                     // tail 0..3 pairs
        int e2 = 2 * k + r;
        float p = (e2 < cnt) ? sp[e2 * HEADS + h2] : 0.0f;
        uint2 qq = q[0];
        a0 += p * __uint_as_float(qq.x << 16);
        a1 += p * __uint_as_float(qq.x & 0xFFFF0000u);
        a2 += p * __uint_as_float(qq.y << 16);
        a3 += p * __uint_as_float(qq.y & 0xFFFF0000u);
#pragma unroll
        for (int u = 0; u < 7; ++u) q[u] = q[u + 1];
    }
#undef LP

    a0 += __shfl_xor(a0, 32);
    a1 += __shfl_xor(a1, 32);
    a2 += __shfl_xor(a2, 32);
    a3 += __shfl_xor(a3, 32);

    float denom = __shfl(myl, h2 * 8);
    float inv = 1.0f / fmaxf(denom, 1e-10f);

    if (lane < 32) {
        float4 o4 = make_float4(a0 * inv, a1 * inv, a2 * inv, a3 * inv);
        ((float4*)(out + (size_t)n * CHANNELS))[l32] = o4;
    }
}

// ---------------------------------------------------------------------------
extern "C" void kernel_launch(void* const* d_in, const int* in_sizes, int n_in,
                              void* d_out, int out_size, void* d_ws, size_t ws_size,
                              hipStream_t stream) {
    const float* x   = (const float*)d_in[0];
    const int*   ei  = (const int*)  d_in[1];   // (2, N_EDGES) row-major
    const float* att = (const float*)d_in[2];
    const int* src = ei;
    const int* dst = ei + N_EDGES;
    float* out = (float*)d_out;

    // Workspace layout (no memsets needed — every read location written first):
    int*            hist   = (int*)d_ws;                       // NBINS*NCHUNK
    int*            offm   = hist + (size_t)NBINS * NCHUNK;    // NCHUNK*NBINS
    int*            bincnt = offm + (size_t)NCHUNK * NBINS;    // NBINS
    unsigned*       ebuf   = (unsigned*)(bincnt + NBINS);      // NBINS*SEGCAP
    int*            cursor = (int*)(ebuf + (size_t)NBINS * SEGCAP);
    unsigned short* bucket = (unsigned short*)(cursor + N_NODES);
    float*          ls8    = (float*)(bucket + (size_t)N_NODES * CAP);
    float*          ld8    = ls8 + (size_t)N_NODES * HEADS;
    unsigned short* xb     = (unsigned short*)(ld8 + (size_t)N_NODES * HEADS);

    hist_logit_kernel<<<NCHUNK + LOGIT_VB, 256, 0, stream>>>(
        x, att, dst, hist, ls8, ld8, xb);
    scan_kernel<<<NBINS, 256, 0, stream>>>(hist, offm, bincnt);
    binscatter_kernel<<<NCHUNK, 256, 0, stream>>>(src, dst, offm, ebuf);
    bucket_kernel<<<NBINS, 256, 0, stream>>>(ebuf, bincnt, cursor, bucket);
    fused_gat_kernel<<<(N_NODES + WPB - 1) / WPB, 64 * WPB, 0, stream>>>(
        xb, ls8, ld8, cursor, bucket, out);
}